// Round 4
// baseline (143.675 us; speedup 1.0000x reference)
//
#include <hip/hip_runtime.h>

#define N 8192
#define FIN 256
#define FOUT 64
#define ALPHA 0.2f
#define LOG2C 4
#define NCHUNK (1 << LOG2C)
#define CLEN (N >> LOG2C)        // 512 j per chunk

typedef float f32x4 __attribute__((ext_vector_type(4)));
typedef short s16x4 __attribute__((ext_vector_type(4)));
typedef short s16x8 __attribute__((ext_vector_type(8)));

static __device__ __forceinline__ unsigned short f2bf(float x) {
    unsigned u = __float_as_uint(x);
    u += 0x7fffu + ((u >> 16) & 1u);
    return (unsigned short)(u >> 16);
}

// ---------------- Kernel 1: h = input@W + b_lin ---------------------------------------
// hTf layout: 32-j-major tiles, element (f,j) at (j>>5)*2048 + f*32 + (j&31)  [bf16]
// Also writes s1, s2 and atomicMax's global s2 max (monotone-uint encoding).
__global__ __launch_bounds__(256) void k_linear(
    const float* __restrict__ input, const float* __restrict__ W,
    const float* __restrict__ b_lin, const float* __restrict__ a,
    unsigned short* __restrict__ hTf, float* __restrict__ s1, float* __restrict__ s2,
    unsigned* __restrict__ s2max_enc)
{
    __shared__ float in_sh[16 * FIN];     // 16 KB
    __shared__ float hst[64][17];         // transpose staging, stride 17 = conflict-free
    int t = threadIdx.x, w = t >> 6, f = t & 63;
    int b = blockIdx.x;
    int i0 = b * 16;

#pragma unroll
    for (int r = 0; r < 4; r++) {
        int row = w * 4 + r;
        *(float4*)&in_sh[row * FIN + f * 4] =
            *(const float4*)(input + (size_t)(i0 + row) * FIN + f * 4);
    }

    float a1v = a[f], a2v = a[FOUT + f];
    float h[4];
#pragma unroll
    for (int r = 0; r < 4; r++) h[r] = b_lin[f];

    for (int k4 = 0; k4 < FIN / 4; k4++) {
        float wv0 = W[(k4 * 4 + 0) * FOUT + f];
        float wv1 = W[(k4 * 4 + 1) * FOUT + f];
        float wv2 = W[(k4 * 4 + 2) * FOUT + f];
        float wv3 = W[(k4 * 4 + 3) * FOUT + f];
#pragma unroll
        for (int r = 0; r < 4; r++) {
            float4 iv = *(const float4*)&in_sh[(w * 4 + r) * FIN + k4 * 4];
            h[r] = fmaf(iv.x, wv0, h[r]);
            h[r] = fmaf(iv.y, wv1, h[r]);
            h[r] = fmaf(iv.z, wv2, h[r]);
            h[r] = fmaf(iv.w, wv3, h[r]);
        }
    }

    float wmax = -1e30f;
#pragma unroll
    for (int r = 0; r < 4; r++) {
        hst[f][w * 4 + r] = h[r];
        float v1 = h[r] * a1v, v2 = h[r] * a2v;
#pragma unroll
        for (int d = 1; d < 64; d <<= 1) { v1 += __shfl_xor(v1, d); v2 += __shfl_xor(v2, d); }
        wmax = fmaxf(wmax, v2);
        if (f == 0) { s1[i0 + w * 4 + r] = v1; s2[i0 + w * 4 + r] = v2; }
    }
    if (f == 0) {
        unsigned u = __float_as_uint(wmax);
        unsigned key = (u & 0x80000000u) ? ~u : (u | 0x80000000u);
        atomicMax(s2max_enc, key);
    }
    __syncthreads();

    // this block covers j = b*16 .. b*16+15 -> halves of 32-j tiles
    int fo = t >> 2, seg = t & 3;
    unsigned lo = f2bf(hst[fo][seg * 4 + 0]) | ((unsigned)f2bf(hst[fo][seg * 4 + 1]) << 16);
    unsigned hi = f2bf(hst[fo][seg * 4 + 2]) | ((unsigned)f2bf(hst[fo][seg * 4 + 3]) << 16);
    int2 v; v.x = (int)lo; v.y = (int)hi;
    size_t base = (size_t)(b >> 1) * 2048 + (size_t)fo * 32 + (b & 1) * 16 + seg * 4;
    *(int2*)(hTf + base) = v;
}

// ---------------- Kernel 2: fused mask + exp + P@H via mfma 16x16x32 ------------------
// 1024 blocks x 512 threads (8 waves). chunk = bid&15 (consistent XCD), rowgroup=bid>>4
// owns 128 rows (wave w -> rows rg*128+w*16..+15). Chunk's hT slice (64 KB) + scaled s2
// (2 KB) staged in LDS once -> 66 KB -> 2 blocks/CU (4 waves/SIMD). One barrier total;
// j-loop fully unrolled (8 iters), depth-2 adj prefetch, conflict-free b128 B-reads.
__global__ __launch_bounds__(512, 4) void k_attn(
    const int* __restrict__ adj, const float* __restrict__ s1g,
    const float* __restrict__ s2g, const unsigned short* __restrict__ hTf,
    const unsigned* __restrict__ s2max_enc,
    float* __restrict__ numP, float* __restrict__ denP)
{
    extern __shared__ char smem[];
    unsigned short* hsh = (unsigned short*)smem;            // 64 KB: 16 tiles x 2048
    float* s2sh = (float*)(smem + 64 * CLEN * 2);           // 2 KB (pre-scaled by LOG2E)

    const float LOG2E = 1.4426950408889634f;
    int bid = blockIdx.x;
    int chunk = bid & (NCHUNK - 1);
    int rg = bid >> LOG2C;
    int jstart = chunk * CLEN;
    int t = threadIdx.x, w = t >> 6, l = t & 63;
    int l15 = l & 15, kg = l >> 4;

    // ---- stage hT slice (contiguous 64 KB) + scaled s2, one barrier ----
    {
        const int4* src = (const int4*)(hTf + (size_t)jstart * 64);
        int4* dst = (int4*)hsh;
#pragma unroll
        for (int k = 0; k < 8; k++) dst[t + k * 512] = src[t + k * 512];
        s2sh[t] = s2g[jstart + t] * LOG2E;
    }
    unsigned key = *s2max_enc;
    unsigned su = (key & 0x80000000u) ? (key ^ 0x80000000u) : ~key;
    float s2m = __uint_as_float(su);
    __syncthreads();

    int i0 = rg * 128;
    int i = i0 + w * 16 + l15;                          // this lane's P-row
    float s1v = s1g[i];
    float mx = s1v + s2m; mx = fmaxf(mx, ALPHA * mx);   // leaky(s1+s2max) >= rowmax
    float m2 = mx * LOG2E;
    float s1c = fmaf(s1v, LOG2E, -m2);                  // u = s1c + s2L[j]
    float c2 = -0.8f * m2;                              // arg = max(u, 0.2u + c2)

    // adj int4 stream for this row: index = it*16 + kb32*8 + kg*2 + {0,1}
    const int4* adjq = (const int4*)(adj + (size_t)i * N + jstart);
    int4 a0[4], a1[4];
#pragma unroll
    for (int kb = 0; kb < 2; kb++) {
        a0[kb * 2 + 0] = adjq[kb * 8 + kg * 2 + 0];
        a0[kb * 2 + 1] = adjq[kb * 8 + kg * 2 + 1];
        a1[kb * 2 + 0] = adjq[16 + kb * 8 + kg * 2 + 0];
        a1[kb * 2 + 1] = adjq[16 + kb * 8 + kg * 2 + 1];
    }

    f32x4 acc[4] = {};
    float dacc = 0.f;

#pragma unroll
    for (int it = 0; it < CLEN / 64; it++) {
        int4 anext[4];
        if (it + 2 < CLEN / 64) {
#pragma unroll
            for (int kb = 0; kb < 2; kb++) {
                anext[kb * 2 + 0] = adjq[(it + 2) * 16 + kb * 8 + kg * 2 + 0];
                anext[kb * 2 + 1] = adjq[(it + 2) * 16 + kb * 8 + kg * 2 + 1];
            }
        }
        // A fragments (P) for mfma 16x16x32: row=l15, k=kg*8+e (e=0..7)
        s16x8 afr[2];
#pragma unroll
        for (int kb = 0; kb < 2; kb++) {
            const float* svp = &s2sh[it * 64 + kb * 32 + kg * 8];
            float4 sv0 = *(const float4*)(svp);
            float4 sv1 = *(const float4*)(svp + 4);
            int4 av0 = a0[kb * 2 + 0];
            int4 av1 = a0[kb * 2 + 1];
            float p[8];
            { float u = s1c + sv0.x; float g = fmaxf(u, fmaf(0.2f, u, c2)); p[0] = (av0.x > 0) ? exp2f(g) : 0.f; }
            { float u = s1c + sv0.y; float g = fmaxf(u, fmaf(0.2f, u, c2)); p[1] = (av0.y > 0) ? exp2f(g) : 0.f; }
            { float u = s1c + sv0.z; float g = fmaxf(u, fmaf(0.2f, u, c2)); p[2] = (av0.z > 0) ? exp2f(g) : 0.f; }
            { float u = s1c + sv0.w; float g = fmaxf(u, fmaf(0.2f, u, c2)); p[3] = (av0.w > 0) ? exp2f(g) : 0.f; }
            { float u = s1c + sv1.x; float g = fmaxf(u, fmaf(0.2f, u, c2)); p[4] = (av1.x > 0) ? exp2f(g) : 0.f; }
            { float u = s1c + sv1.y; float g = fmaxf(u, fmaf(0.2f, u, c2)); p[5] = (av1.y > 0) ? exp2f(g) : 0.f; }
            { float u = s1c + sv1.z; float g = fmaxf(u, fmaf(0.2f, u, c2)); p[6] = (av1.z > 0) ? exp2f(g) : 0.f; }
            { float u = s1c + sv1.w; float g = fmaxf(u, fmaf(0.2f, u, c2)); p[7] = (av1.w > 0) ? exp2f(g) : 0.f; }
            dacc += ((p[0] + p[1]) + (p[2] + p[3])) + ((p[4] + p[5]) + (p[6] + p[7]));
            s16x8 af;
#pragma unroll
            for (int e = 0; e < 8; e++) af[e] = (short)f2bf(p[e]);
            afr[kb] = af;
        }
        // B fragments from LDS, tile = it*2+kb32; lane addr l15*64B + kg*16B: uniform
        // 8 touches/bank -> conflict-free b128
#pragma unroll
        for (int nt = 0; nt < 4; nt++) {
            const unsigned short* bq = hsh + (size_t)(it * 2) * 2048 + (nt * 16 + l15) * 32 + kg * 8;
            s16x8 b0 = *(const s16x8*)(bq);
            s16x8 b1 = *(const s16x8*)(bq + 2048);
            acc[nt] = __builtin_amdgcn_mfma_f32_16x16x32_bf16(afr[0], b0, acc[nt], 0, 0, 0);
            acc[nt] = __builtin_amdgcn_mfma_f32_16x16x32_bf16(afr[1], b1, acc[nt], 0, 0, 0);
        }
#pragma unroll
        for (int kb = 0; kb < 4; kb++) { a0[kb] = a1[kb]; a1[kb] = anext[kb]; }
    }

    dacc += __shfl_xor(dacc, 16);
    dacc += __shfl_xor(dacc, 32);
    if (l < 16) denP[(size_t)chunk * N + i0 + w * 16 + l] = dacc;
#pragma unroll
    for (int nt = 0; nt < 4; nt++) {
#pragma unroll
        for (int r = 0; r < 4; r++) {
            int orow = w * 16 + kg * 4 + r;   // C layout: row=(l>>4)*4+r, col=l&15
            numP[((size_t)chunk * N + i0 + orow) * FOUT + nt * 16 + l15] = acc[nt][r];
        }
    }
}

// ---------------- Kernel 3: combine chunk partials, divide, add bias ------------------
__global__ __launch_bounds__(256) void k_finalize(
    const float* __restrict__ numP, const float* __restrict__ denP,
    const float* __restrict__ bias, float* __restrict__ out)
{
    int idx = blockIdx.x * 256 + threadIdx.x;
    int i = idx >> 6, f = idx & 63;
    float nsum = 0.f, dsum = 0.f;
#pragma unroll
    for (int c = 0; c < NCHUNK; c++) {
        nsum += numP[(size_t)c * (N * FOUT) + idx];
        dsum += denP[(size_t)c * N + i];
    }
    out[idx] = nsum / dsum + bias[f];
}

extern "C" void kernel_launch(void* const* d_in, const int* in_sizes, int n_in,
                              void* d_out, int out_size, void* d_ws, size_t ws_size,
                              hipStream_t stream)
{
    const float* input = (const float*)d_in[0];
    const int*   adj   = (const int*)d_in[1];
    const float* W     = (const float*)d_in[2];
    const float* b_lin = (const float*)d_in[3];
    const float* a     = (const float*)d_in[4];
    const float* bias  = (const float*)d_in[5];
    float* out = (float*)d_out;

    char* ws = (char*)d_ws;
    unsigned short* hTf = (unsigned short*)ws;                   // 1 MiB
    float* s1    = (float*)(ws + 1048576);                       // 32 KB
    float* s2    = (float*)(ws + 1048576 + 32768);               // 32 KB
    unsigned* s2max_enc = (unsigned*)(ws + 1048576 + 65536);     // 4 B (padded to 256)
    size_t fixed = 1048576 + 65536 + 256;
    float* numP = (float*)(ws + fixed);                          // 16 x 2 MiB
    float* denP = (float*)(ws + fixed + ((size_t)N * FOUT * 4) * NCHUNK);

    size_t smem = (size_t)64 * CLEN * 2 + CLEN * 4;              // 66 KB
    hipFuncSetAttribute((const void*)k_attn,
                        hipFuncAttributeMaxDynamicSharedMemorySize, (int)smem);

    hipMemsetAsync(s2max_enc, 0, 4, stream);                     // capture-safe
    hipLaunchKernelGGL(k_linear, dim3(512), dim3(256), 0, stream,
                       input, W, b_lin, a, hTf, s1, s2, s2max_enc);
    hipLaunchKernelGGL(k_attn, dim3((N / 128) * NCHUNK), dim3(512), smem, stream,
                       adj, s1, s2, hTf, s2max_enc, numP, denP);
    hipLaunchKernelGGL(k_finalize, dim3(2048), dim3(256), 0, stream,
                       numP, denP, bias, out);
}

// Round 5
// 109.667 us; speedup vs baseline: 1.3101x; 1.3101x over previous
//
#include <hip/hip_runtime.h>

#define N 8192
#define FIN 256
#define FOUT 64
#define ALPHA 0.2f
#define LOG2C 4
#define NCHUNK (1 << LOG2C)
#define CLEN (N >> LOG2C)        // 512 j per chunk

typedef float f32x4 __attribute__((ext_vector_type(4)));
typedef short s16x8 __attribute__((ext_vector_type(8)));

static __device__ __forceinline__ unsigned short f2bf(float x) {
    unsigned u = __float_as_uint(x);
    u += 0x7fffu + ((u >> 16) & 1u);
    return (unsigned short)(u >> 16);
}

// ---------------- Kernel 1: h = input@W + b_lin ---------------------------------------
// hTf layout: 32-j-major tiles, element (f,j) at (j>>5)*2048 + f*32 + (j&31)  [bf16]
__global__ __launch_bounds__(256) void k_linear(
    const float* __restrict__ input, const float* __restrict__ W,
    const float* __restrict__ b_lin, const float* __restrict__ a,
    unsigned short* __restrict__ hTf, float* __restrict__ s1, float* __restrict__ s2,
    unsigned* __restrict__ s2max_enc)
{
    __shared__ float in_sh[16 * FIN];
    __shared__ float hst[64][17];
    int t = threadIdx.x, w = t >> 6, f = t & 63;
    int b = blockIdx.x;
    int i0 = b * 16;

#pragma unroll
    for (int r = 0; r < 4; r++) {
        int row = w * 4 + r;
        *(float4*)&in_sh[row * FIN + f * 4] =
            *(const float4*)(input + (size_t)(i0 + row) * FIN + f * 4);
    }

    float a1v = a[f], a2v = a[FOUT + f];
    float h[4];
#pragma unroll
    for (int r = 0; r < 4; r++) h[r] = b_lin[f];

    for (int k4 = 0; k4 < FIN / 4; k4++) {
        float wv0 = W[(k4 * 4 + 0) * FOUT + f];
        float wv1 = W[(k4 * 4 + 1) * FOUT + f];
        float wv2 = W[(k4 * 4 + 2) * FOUT + f];
        float wv3 = W[(k4 * 4 + 3) * FOUT + f];
#pragma unroll
        for (int r = 0; r < 4; r++) {
            float4 iv = *(const float4*)&in_sh[(w * 4 + r) * FIN + k4 * 4];
            h[r] = fmaf(iv.x, wv0, h[r]);
            h[r] = fmaf(iv.y, wv1, h[r]);
            h[r] = fmaf(iv.z, wv2, h[r]);
            h[r] = fmaf(iv.w, wv3, h[r]);
        }
    }

    float wmax = -1e30f;
#pragma unroll
    for (int r = 0; r < 4; r++) {
        hst[f][w * 4 + r] = h[r];
        float v1 = h[r] * a1v, v2 = h[r] * a2v;
#pragma unroll
        for (int d = 1; d < 64; d <<= 1) { v1 += __shfl_xor(v1, d); v2 += __shfl_xor(v2, d); }
        wmax = fmaxf(wmax, v2);
        if (f == 0) { s1[i0 + w * 4 + r] = v1; s2[i0 + w * 4 + r] = v2; }
    }
    if (f == 0) {
        unsigned u = __float_as_uint(wmax);
        unsigned key = (u & 0x80000000u) ? ~u : (u | 0x80000000u);
        atomicMax(s2max_enc, key);
    }
    __syncthreads();

    int fo = t >> 2, seg = t & 3;
    unsigned lo = f2bf(hst[fo][seg * 4 + 0]) | ((unsigned)f2bf(hst[fo][seg * 4 + 1]) << 16);
    unsigned hi = f2bf(hst[fo][seg * 4 + 2]) | ((unsigned)f2bf(hst[fo][seg * 4 + 3]) << 16);
    int2 v; v.x = (int)lo; v.y = (int)hi;
    size_t base = (size_t)(b >> 1) * 2048 + (size_t)fo * 32 + (b & 1) * 16 + seg * 4;
    *(int2*)(hTf + base) = v;
}

// ---------------- Kernel 2: fused mask + exp + P@H via mfma 16x16x32 ------------------
// 1024 blocks x 512 threads. chunk=bid&15 (XCD-consistent), rowgroup=bid>>4 owns 128
// rows. hT slice (64 KB, XOR-swizzled granules) + scaled s2 staged once -> one barrier;
// unroll-2 double-buffered adj prefetch (a0/a1 role swap, no reg rotation).

// P-gen: 8 elements from one 32-j block; packs to bf16 via v_cvt_pk_bf16_f32
#define PGEN(AV0, AV1, SVP, AFR) do {                                             \
    float4 sv0 = *(const float4*)(SVP);                                           \
    float4 sv1 = *(const float4*)((SVP) + 4);                                     \
    float p0, p1, p2, p3, p4, p5, p6, p7;                                         \
    { float u = s1c + sv0.x; float g = fmaxf(u, fmaf(0.2f, u, c2)); p0 = (AV0.x > 0) ? exp2f(g) : 0.f; } \
    { float u = s1c + sv0.y; float g = fmaxf(u, fmaf(0.2f, u, c2)); p1 = (AV0.y > 0) ? exp2f(g) : 0.f; } \
    { float u = s1c + sv0.z; float g = fmaxf(u, fmaf(0.2f, u, c2)); p2 = (AV0.z > 0) ? exp2f(g) : 0.f; } \
    { float u = s1c + sv0.w; float g = fmaxf(u, fmaf(0.2f, u, c2)); p3 = (AV0.w > 0) ? exp2f(g) : 0.f; } \
    { float u = s1c + sv1.x; float g = fmaxf(u, fmaf(0.2f, u, c2)); p4 = (AV1.x > 0) ? exp2f(g) : 0.f; } \
    { float u = s1c + sv1.y; float g = fmaxf(u, fmaf(0.2f, u, c2)); p5 = (AV1.y > 0) ? exp2f(g) : 0.f; } \
    { float u = s1c + sv1.z; float g = fmaxf(u, fmaf(0.2f, u, c2)); p6 = (AV1.z > 0) ? exp2f(g) : 0.f; } \
    { float u = s1c + sv1.w; float g = fmaxf(u, fmaf(0.2f, u, c2)); p7 = (AV1.w > 0) ? exp2f(g) : 0.f; } \
    dacc += ((p0 + p1) + (p2 + p3)) + ((p4 + p5) + (p6 + p7));                    \
    union { s16x8 v; unsigned u[4]; } pk;                                         \
    asm("v_cvt_pk_bf16_f32 %0, %1, %2" : "=v"(pk.u[0]) : "v"(p0), "v"(p1));       \
    asm("v_cvt_pk_bf16_f32 %0, %1, %2" : "=v"(pk.u[1]) : "v"(p2), "v"(p3));       \
    asm("v_cvt_pk_bf16_f32 %0, %1, %2" : "=v"(pk.u[2]) : "v"(p4), "v"(p5));       \
    asm("v_cvt_pk_bf16_f32 %0, %1, %2" : "=v"(pk.u[3]) : "v"(p6), "v"(p7));       \
    AFR = pk.v;                                                                   \
} while (0)

#define BODY(AREG, IT) do {                                                       \
    s16x8 afr0, afr1;                                                             \
    const float* svp = &s2sh[(IT) * 64 + kg * 8];                                 \
    PGEN(AREG[0], AREG[1], svp, afr0);                                            \
    PGEN(AREG[2], AREG[3], svp + 32, afr1);                                       \
    if ((IT) + 2 < CLEN / 64) {                                                   \
        AREG[0] = adjq[((IT) + 2) * 16 + kg * 2 + 0];                             \
        AREG[1] = adjq[((IT) + 2) * 16 + kg * 2 + 1];                             \
        AREG[2] = adjq[((IT) + 2) * 16 + 8 + kg * 2 + 0];                         \
        AREG[3] = adjq[((IT) + 2) * 16 + 8 + kg * 2 + 1];                         \
    }                                                                             \
    const unsigned short* bt = hsh + (size_t)((IT) * 2) * 2048 + l15 * 32 + kgs * 8; \
    _Pragma("unroll")                                                             \
    for (int nt = 0; nt < 4; nt++) {                                              \
        const unsigned short* bq = bt + nt * 512;                                 \
        s16x8 b0 = *(const s16x8*)(bq);                                           \
        s16x8 b1 = *(const s16x8*)(bq + 2048);                                    \
        acc[nt] = __builtin_amdgcn_mfma_f32_16x16x32_bf16(afr0, b0, acc[nt], 0, 0, 0); \
        acc[nt] = __builtin_amdgcn_mfma_f32_16x16x32_bf16(afr1, b1, acc[nt], 0, 0, 0); \
    }                                                                             \
} while (0)

__global__ __launch_bounds__(512, 4) void k_attn(
    const int* __restrict__ adj, const float* __restrict__ s1g,
    const float* __restrict__ s2g, const unsigned short* __restrict__ hTf,
    const unsigned* __restrict__ s2max_enc,
    float* __restrict__ numP, float* __restrict__ denP)
{
    extern __shared__ char smem[];
    unsigned short* hsh = (unsigned short*)smem;            // 64 KB, swizzled granules
    float* s2sh = (float*)(smem + 64 * CLEN * 2);           // 2 KB (pre-scaled by LOG2E)

    const float LOG2E = 1.4426950408889634f;
    int bid = blockIdx.x;
    int chunk = bid & (NCHUNK - 1);
    int rg = bid >> LOG2C;
    int jstart = chunk * CLEN;
    int t = threadIdx.x, w = t >> 6, l = t & 63;
    int l15 = l & 15, kg = l >> 4;
    int kgs = kg ^ ((l15 >> 1) & 3);                        // swizzled k-granule

    // ---- stage hT slice with granule swizzle G -> (G&~3)|((G^(G>>3))&3) ----
    {
        const int4* src = (const int4*)(hTf + (size_t)jstart * 64);
        int4* dst = (int4*)hsh;
#pragma unroll
        for (int k = 0; k < 8; k++) {
            int G = t + k * 512;
            int Gs = (G & ~3) | ((G ^ (G >> 3)) & 3);
            dst[Gs] = src[G];
        }
        s2sh[t] = s2g[jstart + t] * LOG2E;
    }
    unsigned key = *s2max_enc;
    unsigned su = (key & 0x80000000u) ? (key ^ 0x80000000u) : ~key;
    float s2m = __uint_as_float(su);
    __syncthreads();

    int i0 = rg * 128;
    int i = i0 + w * 16 + l15;                          // this lane's P-row
    float s1v = s1g[i];
    float mx = s1v + s2m; mx = fmaxf(mx, ALPHA * mx);   // leaky(s1+s2max) >= rowmax
    float m2 = mx * LOG2E;
    float s1c = fmaf(s1v, LOG2E, -m2);
    float c2 = -0.8f * m2;

    const int4* adjq = (const int4*)(adj + (size_t)i * N + jstart);
    int4 a0[4], a1[4];
    a0[0] = adjq[kg * 2 + 0];  a0[1] = adjq[kg * 2 + 1];
    a0[2] = adjq[8 + kg * 2 + 0];  a0[3] = adjq[8 + kg * 2 + 1];
    a1[0] = adjq[16 + kg * 2 + 0]; a1[1] = adjq[16 + kg * 2 + 1];
    a1[2] = adjq[24 + kg * 2 + 0]; a1[3] = adjq[24 + kg * 2 + 1];

    f32x4 acc[4] = {};
    float dacc = 0.f;

#pragma unroll 1
    for (int it = 0; it < CLEN / 64; it += 2) {
        BODY(a0, it);
        BODY(a1, it + 1);
    }

    dacc += __shfl_xor(dacc, 16);
    dacc += __shfl_xor(dacc, 32);
    if (l < 16) denP[(size_t)chunk * N + i0 + w * 16 + l] = dacc;
#pragma unroll
    for (int nt = 0; nt < 4; nt++) {
#pragma unroll
        for (int r = 0; r < 4; r++) {
            int orow = w * 16 + kg * 4 + r;   // C layout: row=(l>>4)*4+r, col=l&15
            numP[((size_t)chunk * N + i0 + orow) * FOUT + nt * 16 + l15] = acc[nt][r];
        }
    }
}

// ---------------- Kernel 3: combine chunk partials, divide, add bias ------------------
__global__ __launch_bounds__(256) void k_finalize(
    const float* __restrict__ numP, const float* __restrict__ denP,
    const float* __restrict__ bias, float* __restrict__ out)
{
    int idx = blockIdx.x * 256 + threadIdx.x;
    int i = idx >> 6, f = idx & 63;
    float nsum = 0.f, dsum = 0.f;
#pragma unroll
    for (int c = 0; c < NCHUNK; c++) {
        nsum += numP[(size_t)c * (N * FOUT) + idx];
        dsum += denP[(size_t)c * N + i];
    }
    out[idx] = nsum / dsum + bias[f];
}

extern "C" void kernel_launch(void* const* d_in, const int* in_sizes, int n_in,
                              void* d_out, int out_size, void* d_ws, size_t ws_size,
                              hipStream_t stream)
{
    const float* input = (const float*)d_in[0];
    const int*   adj   = (const int*)d_in[1];
    const float* W     = (const float*)d_in[2];
    const float* b_lin = (const float*)d_in[3];
    const float* a     = (const float*)d_in[4];
    const float* bias  = (const float*)d_in[5];
    float* out = (float*)d_out;

    char* ws = (char*)d_ws;
    unsigned short* hTf = (unsigned short*)ws;                   // 1 MiB
    float* s1    = (float*)(ws + 1048576);                       // 32 KB
    float* s2    = (float*)(ws + 1048576 + 32768);               // 32 KB
    unsigned* s2max_enc = (unsigned*)(ws + 1048576 + 65536);     // 4 B (padded to 256)
    size_t fixed = 1048576 + 65536 + 256;
    float* numP = (float*)(ws + fixed);                          // 16 x 2 MiB
    float* denP = (float*)(ws + fixed + ((size_t)N * FOUT * 4) * NCHUNK);

    size_t smem = (size_t)64 * CLEN * 2 + CLEN * 4;              // 66 KB
    hipFuncSetAttribute((const void*)k_attn,
                        hipFuncAttributeMaxDynamicSharedMemorySize, (int)smem);

    hipMemsetAsync(s2max_enc, 0, 4, stream);                     // capture-safe
    hipLaunchKernelGGL(k_linear, dim3(512), dim3(256), 0, stream,
                       input, W, b_lin, a, hTf, s1, s2, s2max_enc);
    hipLaunchKernelGGL(k_attn, dim3((N / 128) * NCHUNK), dim3(512), smem, stream,
                       adj, s1, s2, hTf, s2max_enc, numP, denP);
    hipLaunchKernelGGL(k_finalize, dim3(2048), dim3(256), 0, stream,
                       numP, denP, bias, out);
}

// Round 7
// 103.069 us; speedup vs baseline: 1.3940x; 1.0640x over previous
//
#include <hip/hip_runtime.h>

#define N 8192
#define FIN 256
#define FOUT 64
#define ALPHA 0.2f
#define LOG2C 3
#define NCHUNK (1 << LOG2C)
#define CLEN (N >> LOG2C)        // 1024 j per chunk

typedef float f32x4 __attribute__((ext_vector_type(4)));
typedef short s16x8 __attribute__((ext_vector_type(8)));

static __device__ __forceinline__ unsigned short f2bf(float x) {
    unsigned u = __float_as_uint(x);
    u += 0x7fffu + ((u >> 16) & 1u);
    return (unsigned short)(u >> 16);
}

// ---------------- Kernel 1: h = input@W + b_lin ---------------------------------------
// hTf layout: 32-j-major tiles, element (f,j) at (j>>5)*2048 + f*32 + (j&31)  [bf16]
__global__ __launch_bounds__(256) void k_linear(
    const float* __restrict__ input, const float* __restrict__ W,
    const float* __restrict__ b_lin, const float* __restrict__ a,
    unsigned short* __restrict__ hTf, float* __restrict__ s1, float* __restrict__ s2,
    unsigned* __restrict__ s2max_enc)
{
    __shared__ float in_sh[16 * FIN];
    __shared__ float hst[64][17];
    int t = threadIdx.x, w = t >> 6, f = t & 63;
    int b = blockIdx.x;
    int i0 = b * 16;

#pragma unroll
    for (int r = 0; r < 4; r++) {
        int row = w * 4 + r;
        *(float4*)&in_sh[row * FIN + f * 4] =
            *(const float4*)(input + (size_t)(i0 + row) * FIN + f * 4);
    }

    float a1v = a[f], a2v = a[FOUT + f];
    float h[4];
#pragma unroll
    for (int r = 0; r < 4; r++) h[r] = b_lin[f];

    for (int k4 = 0; k4 < FIN / 4; k4++) {
        float wv0 = W[(k4 * 4 + 0) * FOUT + f];
        float wv1 = W[(k4 * 4 + 1) * FOUT + f];
        float wv2 = W[(k4 * 4 + 2) * FOUT + f];
        float wv3 = W[(k4 * 4 + 3) * FOUT + f];
#pragma unroll
        for (int r = 0; r < 4; r++) {
            float4 iv = *(const float4*)&in_sh[(w * 4 + r) * FIN + k4 * 4];
            h[r] = fmaf(iv.x, wv0, h[r]);
            h[r] = fmaf(iv.y, wv1, h[r]);
            h[r] = fmaf(iv.z, wv2, h[r]);
            h[r] = fmaf(iv.w, wv3, h[r]);
        }
    }

    float wmax = -1e30f;
#pragma unroll
    for (int r = 0; r < 4; r++) {
        hst[f][w * 4 + r] = h[r];
        float v1 = h[r] * a1v, v2 = h[r] * a2v;
#pragma unroll
        for (int d = 1; d < 64; d <<= 1) { v1 += __shfl_xor(v1, d); v2 += __shfl_xor(v2, d); }
        wmax = fmaxf(wmax, v2);
        if (f == 0) { s1[i0 + w * 4 + r] = v1; s2[i0 + w * 4 + r] = v2; }
    }
    if (f == 0) {
        unsigned u = __float_as_uint(wmax);
        unsigned key = (u & 0x80000000u) ? ~u : (u | 0x80000000u);
        atomicMax(s2max_enc, key);
    }
    __syncthreads();

    int fo = t >> 2, seg = t & 3;
    unsigned lo = f2bf(hst[fo][seg * 4 + 0]) | ((unsigned)f2bf(hst[fo][seg * 4 + 1]) << 16);
    unsigned hi = f2bf(hst[fo][seg * 4 + 2]) | ((unsigned)f2bf(hst[fo][seg * 4 + 3]) << 16);
    int2 v; v.x = (int)lo; v.y = (int)hi;
    size_t base = (size_t)(b >> 1) * 2048 + (size_t)fo * 32 + (b & 1) * 16 + seg * 4;
    *(int2*)(hTf + base) = v;
}

// ---------------- Kernel 2: fused mask + exp + P@H via mfma 16x16x32 ------------------
// Round-1 structure (proven fastest): 1024 blocks x 256 threads (4 waves x 16 rows),
// small LDS (12.2 KB -> ~5 blocks/CU), per-64-j tile staging with 2 barriers/iter,
// 1-deep adj prefetch. B path = round-5's verified swizzled tiles + b128 reads.

// P-gen: 8 elements of one 32-j subtile; packs to bf16 via v_cvt_pk_bf16_f32
#define PGEN(AV0, AV1, SVP, AFR) do {                                             \
    float4 sv0 = *(const float4*)(SVP);                                           \
    float4 sv1 = *(const float4*)((SVP) + 4);                                     \
    float p0, p1, p2, p3, p4, p5, p6, p7;                                         \
    { float u = s1c + sv0.x; float g = fmaxf(u, fmaf(0.2f, u, c2)); p0 = (AV0.x > 0) ? exp2f(g) : 0.f; } \
    { float u = s1c + sv0.y; float g = fmaxf(u, fmaf(0.2f, u, c2)); p1 = (AV0.y > 0) ? exp2f(g) : 0.f; } \
    { float u = s1c + sv0.z; float g = fmaxf(u, fmaf(0.2f, u, c2)); p2 = (AV0.z > 0) ? exp2f(g) : 0.f; } \
    { float u = s1c + sv0.w; float g = fmaxf(u, fmaf(0.2f, u, c2)); p3 = (AV0.w > 0) ? exp2f(g) : 0.f; } \
    { float u = s1c + sv1.x; float g = fmaxf(u, fmaf(0.2f, u, c2)); p4 = (AV1.x > 0) ? exp2f(g) : 0.f; } \
    { float u = s1c + sv1.y; float g = fmaxf(u, fmaf(0.2f, u, c2)); p5 = (AV1.y > 0) ? exp2f(g) : 0.f; } \
    { float u = s1c + sv1.z; float g = fmaxf(u, fmaf(0.2f, u, c2)); p6 = (AV1.z > 0) ? exp2f(g) : 0.f; } \
    { float u = s1c + sv1.w; float g = fmaxf(u, fmaf(0.2f, u, c2)); p7 = (AV1.w > 0) ? exp2f(g) : 0.f; } \
    dacc += ((p0 + p1) + (p2 + p3)) + ((p4 + p5) + (p6 + p7));                    \
    union { s16x8 v; unsigned u[4]; } pk;                                         \
    asm("v_cvt_pk_bf16_f32 %0, %1, %2" : "=v"(pk.u[0]) : "v"(p0), "v"(p1));       \
    asm("v_cvt_pk_bf16_f32 %0, %1, %2" : "=v"(pk.u[1]) : "v"(p2), "v"(p3));       \
    asm("v_cvt_pk_bf16_f32 %0, %1, %2" : "=v"(pk.u[2]) : "v"(p4), "v"(p5));       \
    asm("v_cvt_pk_bf16_f32 %0, %1, %2" : "=v"(pk.u[3]) : "v"(p6), "v"(p7));       \
    AFR = pk.v;                                                                   \
} while (0)

__global__ __launch_bounds__(256) void k_attn(
    const int* __restrict__ adj, const float* __restrict__ s1g,
    const float* __restrict__ s2g, const unsigned short* __restrict__ hTf,
    const unsigned* __restrict__ s2max_enc,
    float* __restrict__ numP, float* __restrict__ denP)
{
    __shared__ unsigned short hsh[4096];                // 8 KB: one 64-j pair of tiles
    __shared__ float s2sh[CLEN];                        // 4 KB (pre-scaled by LOG2E)

    const float LOG2E = 1.4426950408889634f;
    int bid = blockIdx.x;
    int chunk = bid & (NCHUNK - 1);
    int rg = bid >> LOG2C;
    int jstart = chunk * CLEN;
    int t = threadIdx.x, w = t >> 6, l = t & 63;
    int l15 = l & 15, kg = l >> 4;
    int kgs = kg ^ ((l15 >> 1) & 3);                    // swizzled k-granule (round 5)

    {   // stage scaled s2 slice: 256 threads x float4 = 1024 floats
        float4 sv = ((const float4*)(s2g + jstart))[t];
        sv.x *= LOG2E; sv.y *= LOG2E; sv.z *= LOG2E; sv.w *= LOG2E;
        ((float4*)s2sh)[t] = sv;
    }
    unsigned key = *s2max_enc;
    unsigned su = (key & 0x80000000u) ? (key ^ 0x80000000u) : ~key;
    float s2m = __uint_as_float(su);

    int i0 = rg * 64;
    int i = i0 + w * 16 + l15;                          // this lane's P-row
    float s1v = s1g[i];
    float mx = s1v + s2m; mx = fmaxf(mx, ALPHA * mx);   // leaky(s1+s2max) >= rowmax
    float m2 = mx * LOG2E;
    float s1c = fmaf(s1v, LOG2E, -m2);
    float c2 = -0.8f * m2;

    const int4* adjq = (const int4*)(adj + (size_t)i * N + jstart);
    const int4* src4 = (const int4*)(hTf + (size_t)jstart * 64);

    // 1-deep adj prefetch (round-1 recipe)
    int4 a0 = adjq[kg * 2 + 0];
    int4 a1 = adjq[kg * 2 + 1];
    int4 a2 = adjq[8 + kg * 2 + 0];
    int4 a3 = adjq[8 + kg * 2 + 1];

    f32x4 acc[4] = {};
    float dacc = 0.f;

#pragma unroll 1
    for (int it = 0; it < CLEN / 64; it++) {
        if (it) __syncthreads();                        // prev compute done
        {   // stage 2 tiles (8 KB) with granule swizzle G -> (G&~3)|((G^(G>>3))&3)
            int G0 = t, G1 = t + 256;
            int4 v0 = src4[it * 512 + G0];
            int4 v1 = src4[it * 512 + G1];
            ((int4*)hsh)[(G0 & ~3) | ((G0 ^ (G0 >> 3)) & 3)] = v0;
            ((int4*)hsh)[(G1 & ~3) | ((G1 ^ (G1 >> 3)) & 3)] = v1;
        }
        __syncthreads();                                // staging visible

        int4 n0, n1, n2, n3;
        if (it + 1 < CLEN / 64) {
            n0 = adjq[(it + 1) * 16 + kg * 2 + 0];
            n1 = adjq[(it + 1) * 16 + kg * 2 + 1];
            n2 = adjq[(it + 1) * 16 + 8 + kg * 2 + 0];
            n3 = adjq[(it + 1) * 16 + 8 + kg * 2 + 1];
        }

        const float* svp = &s2sh[it * 64 + kg * 8];
        const unsigned short* bt = hsh + l15 * 32 + kgs * 8;
        // ---- half 0: j-subtile 0 (k = 0..31) ----
        {
            s16x8 afr;
            PGEN(a0, a1, svp, afr);
            s16x8 b0 = *(const s16x8*)(bt);
            s16x8 b1 = *(const s16x8*)(bt + 512);
            s16x8 b2 = *(const s16x8*)(bt + 1024);
            s16x8 b3 = *(const s16x8*)(bt + 1536);
            acc[0] = __builtin_amdgcn_mfma_f32_16x16x32_bf16(afr, b0, acc[0], 0, 0, 0);
            acc[1] = __builtin_amdgcn_mfma_f32_16x16x32_bf16(afr, b1, acc[1], 0, 0, 0);
            acc[2] = __builtin_amdgcn_mfma_f32_16x16x32_bf16(afr, b2, acc[2], 0, 0, 0);
            acc[3] = __builtin_amdgcn_mfma_f32_16x16x32_bf16(afr, b3, acc[3], 0, 0, 0);
        }
        // ---- half 1: j-subtile 1 (k = 32..63) ----
        {
            s16x8 afr;
            PGEN(a2, a3, svp + 32, afr);
            s16x8 b0 = *(const s16x8*)(bt + 2048);
            s16x8 b1 = *(const s16x8*)(bt + 2560);
            s16x8 b2 = *(const s16x8*)(bt + 3072);
            s16x8 b3 = *(const s16x8*)(bt + 3584);
            acc[0] = __builtin_amdgcn_mfma_f32_16x16x32_bf16(afr, b0, acc[0], 0, 0, 0);
            acc[1] = __builtin_amdgcn_mfma_f32_16x16x32_bf16(afr, b1, acc[1], 0, 0, 0);
            acc[2] = __builtin_amdgcn_mfma_f32_16x16x32_bf16(afr, b2, acc[2], 0, 0, 0);
            acc[3] = __builtin_amdgcn_mfma_f32_16x16x32_bf16(afr, b3, acc[3], 0, 0, 0);
        }
        a0 = n0; a1 = n1; a2 = n2; a3 = n3;
    }

    dacc += __shfl_xor(dacc, 16);
    dacc += __shfl_xor(dacc, 32);
    if (l < 16) denP[(size_t)chunk * N + i0 + w * 16 + l] = dacc;
#pragma unroll
    for (int nt = 0; nt < 4; nt++) {
#pragma unroll
        for (int r = 0; r < 4; r++) {
            int orow = w * 16 + kg * 4 + r;   // C layout: row=(l>>4)*4+r, col=l&15
            numP[((size_t)chunk * N + i0 + orow) * FOUT + nt * 16 + l15] = acc[nt][r];
        }
    }
}

// ---------------- Kernel 3: combine chunk partials, divide, add bias ------------------
__global__ __launch_bounds__(256) void k_finalize(
    const float* __restrict__ numP, const float* __restrict__ denP,
    const float* __restrict__ bias, float* __restrict__ out)
{
    int idx = blockIdx.x * 256 + threadIdx.x;
    int i = idx >> 6, f = idx & 63;
    float nsum = 0.f, dsum = 0.f;
#pragma unroll
    for (int c = 0; c < NCHUNK; c++) {
        nsum += numP[(size_t)c * (N * FOUT) + idx];
        dsum += denP[(size_t)c * N + i];
    }
    out[idx] = nsum / dsum + bias[f];
}

extern "C" void kernel_launch(void* const* d_in, const int* in_sizes, int n_in,
                              void* d_out, int out_size, void* d_ws, size_t ws_size,
                              hipStream_t stream)
{
    const float* input = (const float*)d_in[0];
    const int*   adj   = (const int*)d_in[1];
    const float* W     = (const float*)d_in[2];
    const float* b_lin = (const float*)d_in[3];
    const float* a     = (const float*)d_in[4];
    const float* bias  = (const float*)d_in[5];
    float* out = (float*)d_out;

    char* ws = (char*)d_ws;
    unsigned short* hTf = (unsigned short*)ws;                   // 1 MiB
    float* s1    = (float*)(ws + 1048576);                       // 32 KB
    float* s2    = (float*)(ws + 1048576 + 32768);               // 32 KB
    unsigned* s2max_enc = (unsigned*)(ws + 1048576 + 65536);     // 4 B (padded to 256)
    size_t fixed = 1048576 + 65536 + 256;
    float* numP = (float*)(ws + fixed);                          // 8 x 2 MiB
    float* denP = (float*)(ws + fixed + ((size_t)N * FOUT * 4) * NCHUNK);

    hipMemsetAsync(s2max_enc, 0, 4, stream);                     // capture-safe
    hipLaunchKernelGGL(k_linear, dim3(512), dim3(256), 0, stream,
                       input, W, b_lin, a, hTf, s1, s2, s2max_enc);
    hipLaunchKernelGGL(k_attn, dim3((N / 64) * NCHUNK), dim3(256), 0, stream,
                       adj, s1, s2, hTf, s2max_enc, numP, denP);
    hipLaunchKernelGGL(k_finalize, dim3(2048), dim3(256), 0, stream,
                       numP, denP, bias, out);
}